// Round 6
// baseline (641.868 us; speedup 1.0000x reference)
//
#include <hip/hip_runtime.h>
#include <hip/hip_bf16.h>

#define NN 50000
#define NE 800000

__device__ __forceinline__ float2 bfp(uint32_t u) {
    union { uint32_t i; float f; } lo, hi;
    lo.i = u << 16;
    hi.i = u & 0xffff0000u;
    return make_float2(lo.f, hi.f);
}
__device__ __forceinline__ float bf1(uint16_t u) {
    union { uint32_t i; float f; } x; x.i = ((uint32_t)u) << 16; return x.f;
}

// ---------------------------------------------------------------------------
// Fused node GEMM: q (f32, pre-scaled by 1/8), kv (bf16 interleaved [N,2M]),
// skip (f32). x:[N,K] row-major, W:[K,M].
// ---------------------------------------------------------------------------
template<int K, int M, int NODES>
__global__ __launch_bounds__(128)
void node_gemm_qkvs(const float* __restrict__ x,
                    const float* __restrict__ Wq, const float* __restrict__ bq, float* __restrict__ q,
                    const float* __restrict__ Wk, const float* __restrict__ bk,
                    const float* __restrict__ Wv, const float* __restrict__ bv,
                    __hip_bfloat16* __restrict__ kv,
                    const float* __restrict__ Ws, const float* __restrict__ bs, float* __restrict__ skip)
{
    constexpr int SUBS = 128 / M;        // 1 (M=128) or 2 (M=64)
    constexpr int NPS  = NODES / SUBS;   // nodes per sub-group
    __shared__ float xs[NODES][K];
    const int tid = threadIdx.x;
    const int j   = tid % M;
    const int sub = tid / M;
    const int n0  = blockIdx.x * NODES;

    {
        const float4* xsrc = reinterpret_cast<const float4*>(x + (size_t)n0 * K);
        float4* xdst = reinterpret_cast<float4*>(&xs[0][0]);
        #pragma unroll
        for (int i = 0; i < NODES * K / 4 / 128; ++i)
            xdst[tid + i * 128] = xsrc[tid + i * 128];
    }
    __syncthreads();

    float aq[NPS], ak[NPS], av[NPS], as_[NPS];
    #pragma unroll
    for (int i = 0; i < NPS; ++i) { aq[i] = 0.f; ak[i] = 0.f; av[i] = 0.f; as_[i] = 0.f; }

    for (int r = 0; r < K; ++r) {
        const float wq = Wq[r * M + j];
        const float wk = Wk[r * M + j];
        const float wv = Wv[r * M + j];
        const float ws = Ws[r * M + j];
        #pragma unroll
        for (int i = 0; i < NPS; ++i) {
            const float xv = xs[sub * NPS + i][r];
            aq[i] += xv * wq;
            ak[i] += xv * wk;
            av[i] += xv * wv;
            as_[i] += xv * ws;
        }
    }
    const float bbq = bq[j], bbk = bk[j], bbv = bv[j], bbs = bs[j];
    #pragma unroll
    for (int i = 0; i < NPS; ++i) {
        const int row = n0 + sub * NPS + i;
        q[(size_t)row * M + j]    = (aq[i] + bbq) * 0.125f;   // fold 1/sqrt(C)
        skip[(size_t)row * M + j] = as_[i] + bbs;
        kv[(size_t)row * 2 * M + j]     = __float2bfloat16(ak[i] + bbk);
        kv[(size_t)row * 2 * M + M + j] = __float2bfloat16(av[i] + bbv);
    }
}

// ---------------------------------------------------------------------------
// CSR build: histogram -> scan -> scatter-with-payload (dst-sorted srcs + bf16 ea)
// ---------------------------------------------------------------------------
__global__ __launch_bounds__(256)
void hist_dst(const int* __restrict__ dst, int* __restrict__ cnt)
{
    const int e = blockIdx.x * 256 + threadIdx.x;
    if (e < NE) atomicAdd(&cnt[dst[e]], 1);
}

__global__ __launch_bounds__(1024)
void scan_off(const int* __restrict__ cnt, int* __restrict__ off, int* __restrict__ cursor)
{
    __shared__ int part[1024];
    const int tid = threadIdx.x;
    const int C = (NN + 1023) / 1024;
    const int base = tid * C;
    int s = 0;
    for (int i = 0; i < C; ++i) { const int idx = base + i; if (idx < NN) s += cnt[idx]; }
    part[tid] = s;
    __syncthreads();
    const int own = s;
    for (int d = 1; d < 1024; d <<= 1) {
        const int t = (tid >= d) ? part[tid - d] : 0;
        __syncthreads();
        part[tid] += t;
        __syncthreads();
    }
    int run = part[tid] - own;
    for (int i = 0; i < C; ++i) {
        const int idx = base + i;
        if (idx < NN) { off[idx] = run; cursor[idx] = run; run += cnt[idx]; }
    }
    if (tid == 1023) off[NN] = run;
}

__global__ __launch_bounds__(256)
void scatter_edges(const int* __restrict__ dst, const int* __restrict__ src,
                   const float* __restrict__ ea, int* __restrict__ cursor,
                   int* __restrict__ srcs, __hip_bfloat16* __restrict__ eap)
{
    const int e = blockIdx.x * 256 + threadIdx.x;
    if (e >= NE) return;
    const int p = atomicAdd(&cursor[dst[e]], 1);
    srcs[p] = src[e];
    const float4* ea4 = reinterpret_cast<const float4*>(ea) + (size_t)e * 4;
    const float4 a0 = ea4[0], a1 = ea4[1], a2 = ea4[2], a3 = ea4[3];
    const float af[16] = {a0.x,a0.y,a0.z,a0.w, a1.x,a1.y,a1.z,a1.w,
                          a2.x,a2.y,a2.z,a2.w, a3.x,a3.y,a3.z,a3.w};
    __hip_bfloat16 tmp[16];
    #pragma unroll
    for (int r = 0; r < 16; ++r) tmp[r] = __float2bfloat16(af[r]);
    uint4* dp = reinterpret_cast<uint4*>(eap + (size_t)p * 16);
    dp[0] = *reinterpret_cast<const uint4*>(&tmp[0]);
    dp[1] = *reinterpret_cast<const uint4*>(&tmp[8]);
}

// ---------------------------------------------------------------------------
// wq precompute: wq_h[n,r] = sum_c We[r, h*64+c] * q[n, h*64+c]  (q pre-scaled)
// One wave per node; lane owns channel pair; 5-step butterfly per 32-half.
// ---------------------------------------------------------------------------
__global__ __launch_bounds__(256)
void wq_l1(const float* __restrict__ q, const float* __restrict__ We, float* __restrict__ wq)
{
    __shared__ float wes[16 * 128];
    for (int i = threadIdx.x; i < 16 * 128; i += 256) wes[i] = We[i];
    __syncthreads();
    const int node = blockIdx.x * 4 + (threadIdx.x >> 6);
    const int lane = threadIdx.x & 63;
    const int hl = lane & 31;
    const int head = lane >> 5;
    const int c = lane * 2;
    const float2 qp = *reinterpret_cast<const float2*>(q + (size_t)node * 128 + c);
    float myout = 0.f;
    #pragma unroll
    for (int r = 0; r < 16; ++r) {
        const float2 w = *reinterpret_cast<const float2*>(&wes[r * 128 + c]);
        float part = w.x * qp.x + w.y * qp.y;
        #pragma unroll
        for (int m = 1; m < 32; m <<= 1) part += __shfl_xor(part, m, 64);
        if (hl == r) myout = part;
    }
    if (hl < 16) wq[(size_t)node * 32 + head * 16 + hl] = myout;
}

__global__ __launch_bounds__(256)
void wq_l2(const float* __restrict__ q, const float* __restrict__ We, float* __restrict__ wq)
{
    __shared__ float wes[16 * 64];
    for (int i = threadIdx.x; i < 16 * 64; i += 256) wes[i] = We[i];
    __syncthreads();
    const int node = blockIdx.x * 4 + (threadIdx.x >> 6);
    const int lane = threadIdx.x & 63;
    const int hl = lane & 31;
    const int c = hl * 2;
    const float2 qp = *reinterpret_cast<const float2*>(q + (size_t)node * 64 + c);
    float myout = 0.f;
    #pragma unroll
    for (int r = 0; r < 16; ++r) {
        const float2 w = *reinterpret_cast<const float2*>(&wes[r * 64 + c]);
        float part = w.x * qp.x + w.y * qp.y;
        #pragma unroll
        for (int m = 1; m < 32; m <<= 1) part += __shfl_xor(part, m, 64);
        if (hl == r) myout = part;
    }
    if (lane < 16) wq[(size_t)node * 16 + hl] = myout;
}

// ---------------------------------------------------------------------------
// Layer-1 aggregation with the linear factorization:
//   alpha = q·k[src] + ea·wq[dst]     (ea-term: 1 FMA on lanes 0-15 per half)
//   agg   = (Σ ex·v[src] + (Σ ex·ea)@We) / den
// One wave per dst node; lane owns channel pair; head = lane>>5.
// ---------------------------------------------------------------------------
__global__ __launch_bounds__(256)
void agg_l1(const int* __restrict__ off, const int* __restrict__ srcs,
            const __hip_bfloat16* __restrict__ eap,    // [E,16] bf16, dst-sorted
            const float* __restrict__ We,              // [16,128]
            const float* __restrict__ q,               // [N,128], pre-scaled
            const float* __restrict__ wq,              // [N,32]
            const __hip_bfloat16* __restrict__ kv,     // [N,256] k|v  (bf16)
            const float* __restrict__ skip, float* __restrict__ h)
{
    __shared__ float wes[16 * 128];
    for (int i = threadIdx.x; i < 16 * 128; i += 256) wes[i] = We[i];
    __syncthreads();

    const int node = blockIdx.x * 4 + (threadIdx.x >> 6);
    const int lane = threadIdx.x & 63;
    const int hl = lane & 31;
    const int head = lane >> 5;
    const int c = lane * 2;

    const size_t nb = (size_t)node * 128;
    const float2 qp = *reinterpret_cast<const float2*>(q + nb + c);
    const float wqv = (hl < 16) ? wq[(size_t)node * 32 + head * 16 + hl] : 0.f;
    const uint16_t* kvu = reinterpret_cast<const uint16_t*>(kv);
    const uint16_t* eau = reinterpret_cast<const uint16_t*>(eap);

    float acc0 = 0.f, acc1 = 0.f, den = 0.f, eacc = 0.f;
    const int beg = off[node], end = off[node + 1];

    int i = beg;
    for (; i + 1 < end; i += 2) {
        const int sA = srcs[i], sB = srcs[i + 1];
        const uint32_t kpA = *reinterpret_cast<const uint32_t*>(kvu + (size_t)sA * 256 + c);
        const uint32_t vpA = *reinterpret_cast<const uint32_t*>(kvu + (size_t)sA * 256 + 128 + c);
        const uint32_t kpB = *reinterpret_cast<const uint32_t*>(kvu + (size_t)sB * 256 + c);
        const uint32_t vpB = *reinterpret_cast<const uint32_t*>(kvu + (size_t)sB * 256 + 128 + c);
        float eaA = 0.f, eaB = 0.f;
        if (hl < 16) {
            eaA = bf1(eau[(size_t)i * 16 + hl]);
            eaB = bf1(eau[(size_t)(i + 1) * 16 + hl]);
        }
        const float2 kA = bfp(kpA), vA = bfp(vpA), kB = bfp(kpB), vB = bfp(vpB);
        float pA = fmaf(qp.x, kA.x, fmaf(qp.y, kA.y, eaA * wqv));
        float pB = fmaf(qp.x, kB.x, fmaf(qp.y, kB.y, eaB * wqv));
        #pragma unroll
        for (int m = 1; m < 32; m <<= 1) {
            pA += __shfl_xor(pA, m, 64);
            pB += __shfl_xor(pB, m, 64);
        }
        const float exA = __expf(pA), exB = __expf(pB);
        acc0 = fmaf(exA, vA.x, fmaf(exB, vB.x, acc0));
        acc1 = fmaf(exA, vA.y, fmaf(exB, vB.y, acc1));
        den += exA + exB;
        eacc = fmaf(exA, eaA, fmaf(exB, eaB, eacc));
    }
    if (i < end) {
        const int s = srcs[i];
        const uint32_t kp = *reinterpret_cast<const uint32_t*>(kvu + (size_t)s * 256 + c);
        const uint32_t vp = *reinterpret_cast<const uint32_t*>(kvu + (size_t)s * 256 + 128 + c);
        float eaf = 0.f;
        if (hl < 16) eaf = bf1(eau[(size_t)i * 16 + hl]);
        const float2 kk = bfp(kp), vv = bfp(vp);
        float p = fmaf(qp.x, kk.x, fmaf(qp.y, kk.y, eaf * wqv));
        #pragma unroll
        for (int m = 1; m < 32; m <<= 1) p += __shfl_xor(p, m, 64);
        const float ex = __expf(p);
        acc0 = fmaf(ex, vv.x, acc0);
        acc1 = fmaf(ex, vv.y, acc1);
        den += ex;
        eacc = fmaf(ex, eaf, eacc);
    }

    // per-node projection of the accumulated ea moments through We
    #pragma unroll
    for (int r = 0; r < 16; ++r) {
        const float er = __shfl(eacc, r, 32);          // bcast within 32-half
        const float2 w = *reinterpret_cast<const float2*>(&wes[r * 128 + c]);
        acc0 = fmaf(er, w.x, acc0);
        acc1 = fmaf(er, w.y, acc1);
    }

    const float inv = 1.f / (den + 1e-16f);
    const float2 sk = *reinterpret_cast<const float2*>(skip + nb + c);
    const float r0 = acc0 * inv + sk.x;
    const float r1 = acc1 * inv + sk.y;
    *reinterpret_cast<float2*>(h + nb + c) = make_float2(fmaxf(r0, 0.f), fmaxf(r1, 0.f));
}

// ---------------------------------------------------------------------------
// Layer-2 aggregation, same factorization. Two edges per iteration
// (half-wave each, channel pairs). Writes final output.
// ---------------------------------------------------------------------------
__global__ __launch_bounds__(256)
void agg_l2(const int* __restrict__ off, const int* __restrict__ srcs,
            const __hip_bfloat16* __restrict__ eap,    // [E,16] bf16, dst-sorted
            const float* __restrict__ We,              // [16,64]
            const float* __restrict__ q,               // [N,64], pre-scaled
            const float* __restrict__ wq,              // [N,16]
            const __hip_bfloat16* __restrict__ kv,     // [N,128] k|v (bf16)
            const float* __restrict__ skip, float* __restrict__ out)
{
    __shared__ float wes[16 * 64];
    for (int i = threadIdx.x; i < 16 * 64; i += 256) wes[i] = We[i];
    __syncthreads();

    const int node = blockIdx.x * 4 + (threadIdx.x >> 6);
    const int lane = threadIdx.x & 63;
    const int half = lane >> 5;
    const int hl = lane & 31;
    const int c = hl * 2;

    const size_t nb = (size_t)node * 64;
    const float2 qp = *reinterpret_cast<const float2*>(q + nb + c);
    const float wqv = (hl < 16) ? wq[(size_t)node * 16 + hl] : 0.f;
    const uint16_t* kvu = reinterpret_cast<const uint16_t*>(kv);
    const uint16_t* eau = reinterpret_cast<const uint16_t*>(eap);

    float acc0 = 0.f, acc1 = 0.f, den = 0.f, eacc = 0.f;
    const int beg = off[node], end = off[node + 1];

    for (int i = beg; i < end; i += 2) {
        const int ii = i + half;
        const bool valid = ii < end;
        const int ie = valid ? ii : i;
        const int s = srcs[ie];
        const uint32_t kp = *reinterpret_cast<const uint32_t*>(kvu + (size_t)s * 128 + c);
        const uint32_t vp = *reinterpret_cast<const uint32_t*>(kvu + (size_t)s * 128 + 64 + c);
        float eaf = 0.f;
        if (hl < 16) eaf = bf1(eau[(size_t)ie * 16 + hl]);
        const float2 kk = bfp(kp), vv = bfp(vp);
        float p = fmaf(qp.x, kk.x, fmaf(qp.y, kk.y, eaf * wqv));
        #pragma unroll
        for (int m = 1; m < 32; m <<= 1) p += __shfl_xor(p, m, 64);
        const float ex = valid ? __expf(p) : 0.f;
        acc0 = fmaf(ex, vv.x, acc0);
        acc1 = fmaf(ex, vv.y, acc1);
        den += ex;
        eacc = fmaf(ex, eaf, eacc);
    }

    // combine the two half-wave edge subsets
    acc0 += __shfl_xor(acc0, 32, 64);
    acc1 += __shfl_xor(acc1, 32, 64);
    den  += __shfl_xor(den, 32, 64);
    eacc += __shfl_xor(eacc, 32, 64);

    // project accumulated ea moments through We
    #pragma unroll
    for (int r = 0; r < 16; ++r) {
        const float er = __shfl(eacc, r, 32);
        const float2 w = *reinterpret_cast<const float2*>(&wes[r * 64 + c]);
        acc0 = fmaf(er, w.x, acc0);
        acc1 = fmaf(er, w.y, acc1);
    }

    if (half == 0) {
        const float inv = 1.f / (den + 1e-16f);
        const float2 sk = *reinterpret_cast<const float2*>(skip + nb + c);
        *reinterpret_cast<float2*>(out + nb + c) =
            make_float2(acc0 * inv + sk.x, acc1 * inv + sk.y);
    }
}

extern "C" void kernel_launch(void* const* d_in, const int* in_sizes, int n_in,
                              void* d_out, int out_size, void* d_ws, size_t ws_size,
                              hipStream_t stream) {
    const float* x     = (const float*)d_in[0];
    const int*   ei    = (const int*)  d_in[1];
    const float* eattr = (const float*)d_in[2];
    const float* Wq1 = (const float*)d_in[3],  *bq1 = (const float*)d_in[4];
    const float* Wk1 = (const float*)d_in[5],  *bk1 = (const float*)d_in[6];
    const float* Wv1 = (const float*)d_in[7],  *bv1 = (const float*)d_in[8];
    const float* We1 = (const float*)d_in[9];
    const float* Ws1 = (const float*)d_in[10], *bs1 = (const float*)d_in[11];
    const float* Wq2 = (const float*)d_in[12], *bq2 = (const float*)d_in[13];
    const float* Wk2 = (const float*)d_in[14], *bk2 = (const float*)d_in[15];
    const float* Wv2 = (const float*)d_in[16], *bv2 = (const float*)d_in[17];
    const float* We2 = (const float*)d_in[18];
    const float* Ws2 = (const float*)d_in[19], *bs2 = (const float*)d_in[20];

    const int* srcp = ei;
    const int* dstp = ei + NE;

    // workspace layout (~142 MB)
    float* ws = (float*)d_ws;
    const size_t NM1 = (size_t)NN * 128;
    float* q1    = ws;                      // [N,128] f32
    float* skip1 = q1 + NM1;                // [N,128] f32
    float* h     = skip1 + NM1;             // [N,128] f32
    __hip_bfloat16* kv1 = (__hip_bfloat16*)(h + NM1);         // [N,256] bf16
    __hip_bfloat16* eap = kv1 + (size_t)NN * 256;             // [E,16]  bf16
    int* srcs   = (int*)(eap + (size_t)NE * 16);              // [E]
    int* cnt    = srcs + NE;
    int* off    = cnt + NN;
    int* cursor = off + NN + 1;
    float* wqb  = (float*)(cursor + NN);    // [N,32] f32 (L1) / [N,16] (L2)
    // layer-2 aliases (stream-ordered reuse of dead layer-1 buffers)
    float* q2    = q1;                      // [N,64]
    float* skip2 = skip1;                   // [N,64]
    __hip_bfloat16* kv2 = kv1;              // [N,128] bf16

    // ---- CSR build (dst-sorted srcs + bf16 edge-attr), reused by both layers
    hipMemsetAsync(cnt, 0, (size_t)NN * sizeof(int), stream);
    hist_dst<<<NE / 256, 256, 0, stream>>>(dstp, cnt);
    scan_off<<<1, 1024, 0, stream>>>(cnt, off, cursor);
    scatter_edges<<<NE / 256, 256, 0, stream>>>(dstp, srcp, eattr, cursor, srcs, eap);

    // ---- layer 1 ----
    node_gemm_qkvs<128, 128, 16><<<NN / 16, 128, 0, stream>>>(
        x, Wq1, bq1, q1, Wk1, bk1, Wv1, bv1, kv1, Ws1, bs1, skip1);
    wq_l1<<<NN / 4, 256, 0, stream>>>(q1, We1, wqb);
    agg_l1<<<NN / 4, 256, 0, stream>>>(off, srcs, eap, We1, q1, wqb, kv1, skip1, h);

    // ---- layer 2 ----
    node_gemm_qkvs<128, 64, 16><<<NN / 16, 128, 0, stream>>>(
        h, Wq2, bq2, q2, Wk2, bk2, Wv2, bv2, kv2, Ws2, bs2, skip2);
    wq_l2<<<NN / 4, 256, 0, stream>>>(q2, We2, wqb);
    agg_l2<<<NN / 4, 256, 0, stream>>>(off, srcs, eap, We2, q2, wqb, kv2, skip2, (float*)d_out);
}

// Round 7
// 370.906 us; speedup vs baseline: 1.7305x; 1.7305x over previous
//
#include <hip/hip_runtime.h>
#include <hip/hip_bf16.h>

#define NN 50000
#define NE 800000
#define NSCB 196   // ceil(NN/256)

typedef __attribute__((ext_vector_type(8))) short bf16x8;
typedef __attribute__((ext_vector_type(4))) float f32x4;

__device__ __forceinline__ float2 bfp(uint32_t u) {
    union { uint32_t i; float f; } lo, hi;
    lo.i = u << 16;
    hi.i = u & 0xffff0000u;
    return make_float2(lo.f, hi.f);
}
__device__ __forceinline__ float bf1(uint16_t u) {
    union { uint32_t i; float f; } x; x.i = ((uint32_t)u) << 16; return x.f;
}

// ---------------------------------------------------------------------------
// f32 -> bf16 conversion (8 elems/thread)
// ---------------------------------------------------------------------------
__global__ __launch_bounds__(256)
void cvt_bf16(const float* __restrict__ x, __hip_bfloat16* __restrict__ xb, int n8)
{
    const int t = blockIdx.x * 256 + threadIdx.x;
    if (t >= n8) return;
    const float4 a = reinterpret_cast<const float4*>(x)[(size_t)t * 2];
    const float4 b = reinterpret_cast<const float4*>(x)[(size_t)t * 2 + 1];
    __hip_bfloat16 tmp[8] = {__float2bfloat16(a.x), __float2bfloat16(a.y),
                             __float2bfloat16(a.z), __float2bfloat16(a.w),
                             __float2bfloat16(b.x), __float2bfloat16(b.y),
                             __float2bfloat16(b.z), __float2bfloat16(b.w)};
    reinterpret_cast<uint4*>(xb)[t] = *reinterpret_cast<const uint4*>(tmp);
}

// ---------------------------------------------------------------------------
// Pack W = [Wq|Wk|Wv|Ws] (each [128,M] f32) into MFMA B-fragment order, bf16.
// Frag (s, fg, lane l, j) holds W[k = s*32 + (l>>4)*8 + j][col = fg*16 + (l&15)].
// Also builds concatenated bias bcat[4*M].
// ---------------------------------------------------------------------------
template<int M>
__global__ __launch_bounds__(256)
void pack_w(const float* __restrict__ Wq, const float* __restrict__ Wk,
            const float* __restrict__ Wv, const float* __restrict__ Wsk,
            const float* __restrict__ bq, const float* __restrict__ bk,
            const float* __restrict__ bv, const float* __restrict__ bsk,
            __hip_bfloat16* __restrict__ Wp, float* __restrict__ bcat)
{
    constexpr int NFQ = M / 16;
    constexpr int NF_TOT = 4 * NFQ;
    const int t = blockIdx.x * 256 + threadIdx.x;
    if (t >= 4 * NF_TOT * 64) return;
    const int l  = t & 63;
    const int fg = (t >> 6) % NF_TOT;
    const int s  = t / (64 * NF_TOT);
    const int sec = fg / NFQ;
    const int fl  = fg % NFQ;
    const float* W = sec == 0 ? Wq : sec == 1 ? Wk : sec == 2 ? Wv : Wsk;
    const int col = fl * 16 + (l & 15);
    const int k0  = s * 32 + (l >> 4) * 8;
    __hip_bfloat16 tmp[8];
    #pragma unroll
    for (int j = 0; j < 8; ++j) tmp[j] = __float2bfloat16(W[(size_t)(k0 + j) * M + col]);
    *reinterpret_cast<uint4*>(Wp + ((size_t)(s * NF_TOT + fg) * 64 + l) * 8) =
        *reinterpret_cast<const uint4*>(tmp);
    if (s == 0 && (l >> 4) == 0) {
        const float* B = sec == 0 ? bq : sec == 1 ? bk : sec == 2 ? bv : bsk;
        bcat[fg * 16 + (l & 15)] = B[col];
    }
}

// ---------------------------------------------------------------------------
// MFMA node GEMM: out = xb[N,128]bf16 @ [Wq|Wk|Wv|Ws]. 16 rows/block, 4 waves.
// Wave w covers cols [w*M, (w+1)*M) of the 4M-wide output -> wave-uniform
// epilogue section (0=q f32*0.125, 1=k bf16, 2=v bf16, 3=skip f32).
// ---------------------------------------------------------------------------
template<int M>   // 128 (layer 1) or 64 (layer 2)
__global__ __launch_bounds__(256)
void gemm_mfma(const __hip_bfloat16* __restrict__ xb,
               const __hip_bfloat16* __restrict__ Wp,
               const float* __restrict__ bcat,
               float* __restrict__ q, __hip_bfloat16* __restrict__ kv,
               float* __restrict__ skip)
{
    constexpr int NFRAG = M / 16;       // frags per wave
    constexpr int NF_TOT = 4 * NFRAG;
    const int wid  = threadIdx.x >> 6;
    const int l    = threadIdx.x & 63;
    const int row0 = blockIdx.x * 16;
    const int rowg = row0 + (l & 15);
    const int kb   = l >> 4;

    f32x4 acc[NFRAG];
    #pragma unroll
    for (int f = 0; f < NFRAG; ++f) acc[f] = f32x4{0.f, 0.f, 0.f, 0.f};

    const bf16x8* wp8 = reinterpret_cast<const bf16x8*>(Wp);
    #pragma unroll
    for (int s = 0; s < 4; ++s) {
        const bf16x8 a = *reinterpret_cast<const bf16x8*>(
            xb + (size_t)rowg * 128 + s * 32 + kb * 8);
        #pragma unroll
        for (int f = 0; f < NFRAG; ++f) {
            const bf16x8 b = wp8[(size_t)(s * NF_TOT + wid * NFRAG + f) * 64 + l];
            acc[f] = __builtin_amdgcn_mfma_f32_16x16x32_bf16(a, b, acc[f], 0, 0, 0);
        }
    }

    const int cl = l & 15;
    #pragma unroll
    for (int f = 0; f < NFRAG; ++f) {
        const int cg  = (wid * NFRAG + f) * 16 + cl;   // 0..4M
        const int sec = cg / M;                        // wave-uniform
        const int cm  = cg % M;
        const float bb = bcat[cg];
        #pragma unroll
        for (int j = 0; j < 4; ++j) {
            const int row = row0 + kb * 4 + j;
            const float val = acc[f][j] + bb;
            if (sec == 0)      q[(size_t)row * M + cm] = val * 0.125f;
            else if (sec == 1) kv[(size_t)row * 2 * M + cm] = __float2bfloat16(val);
            else if (sec == 2) kv[(size_t)row * 2 * M + M + cm] = __float2bfloat16(val);
            else               skip[(size_t)row * M + cm] = val;
        }
    }
}

// ---------------------------------------------------------------------------
// CSR build: histogram -> hierarchical scan (3 kernels) -> scatter-with-payload
// ---------------------------------------------------------------------------
__global__ __launch_bounds__(256)
void hist_dst(const int* __restrict__ dst, int* __restrict__ cnt)
{
    const int e = blockIdx.x * 256 + threadIdx.x;
    if (e < NE) atomicAdd(&cnt[dst[e]], 1);
}

__global__ __launch_bounds__(256)
void scan_blk(const int* __restrict__ cnt, int* __restrict__ inc, int* __restrict__ bsum)
{
    __shared__ int s[256];
    const int idx = blockIdx.x * 256 + threadIdx.x;
    const int v = (idx < NN) ? cnt[idx] : 0;
    s[threadIdx.x] = v;
    __syncthreads();
    #pragma unroll
    for (int d = 1; d < 256; d <<= 1) {
        const int t = (threadIdx.x >= d) ? s[threadIdx.x - d] : 0;
        __syncthreads();
        s[threadIdx.x] += t;
        __syncthreads();
    }
    if (idx < NN) inc[idx] = s[threadIdx.x];
    if (threadIdx.x == 255) bsum[blockIdx.x] = s[255];
}

__global__ __launch_bounds__(256)
void scan_top(const int* __restrict__ bsum, int* __restrict__ boff)
{
    __shared__ int s[256];
    const int v = (threadIdx.x < NSCB) ? bsum[threadIdx.x] : 0;
    s[threadIdx.x] = v;
    __syncthreads();
    #pragma unroll
    for (int d = 1; d < 256; d <<= 1) {
        const int t = (threadIdx.x >= d) ? s[threadIdx.x - d] : 0;
        __syncthreads();
        s[threadIdx.x] += t;
        __syncthreads();
    }
    boff[threadIdx.x] = s[threadIdx.x] - v;   // exclusive
}

__global__ __launch_bounds__(256)
void scan_fin(const int* __restrict__ cnt, const int* __restrict__ inc,
              const int* __restrict__ boff, int* __restrict__ off, int* __restrict__ cursor)
{
    const int idx = blockIdx.x * 256 + threadIdx.x;
    if (idx < NN) {
        const int o = inc[idx] - cnt[idx] + boff[blockIdx.x];
        off[idx] = o;
        cursor[idx] = o;
    }
    if (idx == 0) off[NN] = NE;
}

__global__ __launch_bounds__(256)
void scatter_edges(const int* __restrict__ dst, const int* __restrict__ src,
                   const float* __restrict__ ea, int* __restrict__ cursor,
                   int* __restrict__ srcs, __hip_bfloat16* __restrict__ eap)
{
    const int e = blockIdx.x * 256 + threadIdx.x;
    if (e >= NE) return;
    const int p = atomicAdd(&cursor[dst[e]], 1);
    srcs[p] = src[e];
    const float4* ea4 = reinterpret_cast<const float4*>(ea) + (size_t)e * 4;
    const float4 a0 = ea4[0], a1 = ea4[1], a2 = ea4[2], a3 = ea4[3];
    const float af[16] = {a0.x,a0.y,a0.z,a0.w, a1.x,a1.y,a1.z,a1.w,
                          a2.x,a2.y,a2.z,a2.w, a3.x,a3.y,a3.z,a3.w};
    __hip_bfloat16 tmp[16];
    #pragma unroll
    for (int r = 0; r < 16; ++r) tmp[r] = __float2bfloat16(af[r]);
    uint4* dp = reinterpret_cast<uint4*>(eap + (size_t)p * 16);
    dp[0] = *reinterpret_cast<const uint4*>(&tmp[0]);
    dp[1] = *reinterpret_cast<const uint4*>(&tmp[8]);
}

// ---------------------------------------------------------------------------
// Layer-1 aggregation (linear factorization + inline wq). One wave per node.
// Writes h as bf16 (consumed only by the layer-2 MFMA GEMM).
// ---------------------------------------------------------------------------
__global__ __launch_bounds__(256)
void agg_l1(const int* __restrict__ off, const int* __restrict__ srcs,
            const __hip_bfloat16* __restrict__ eap,    // [E,16] bf16, dst-sorted
            const float* __restrict__ We,              // [16,128]
            const float* __restrict__ q,               // [N,128], pre-scaled
            const __hip_bfloat16* __restrict__ kv,     // [N,256] k|v (bf16)
            const float* __restrict__ skip, __hip_bfloat16* __restrict__ hb)
{
    __shared__ float wes[16 * 128];
    for (int i = threadIdx.x; i < 16 * 128; i += 256) wes[i] = We[i];
    __syncthreads();

    const int node = blockIdx.x * 4 + (threadIdx.x >> 6);
    const int lane = threadIdx.x & 63;
    const int hl = lane & 31;
    const int c = lane * 2;

    const size_t nb = (size_t)node * 128;
    const float2 qp = *reinterpret_cast<const float2*>(q + nb + c);
    const uint16_t* kvu = reinterpret_cast<const uint16_t*>(kv);
    const uint16_t* eau = reinterpret_cast<const uint16_t*>(eap);

    // inline wq: wqv (lane hl==r of each half) = sum_c We[r, head*64+c]*q[c]
    float wqv = 0.f;
    #pragma unroll
    for (int r = 0; r < 16; ++r) {
        const float2 w = *reinterpret_cast<const float2*>(&wes[r * 128 + c]);
        float part = fmaf(w.x, qp.x, w.y * qp.y);
        #pragma unroll
        for (int m = 1; m < 32; m <<= 1) part += __shfl_xor(part, m, 64);
        if (hl == r) wqv = part;
    }

    float acc0 = 0.f, acc1 = 0.f, den = 0.f, eacc = 0.f;
    const int beg = off[node], end = off[node + 1];

    int i = beg;
    for (; i + 1 < end; i += 2) {
        const int sA = srcs[i], sB = srcs[i + 1];
        const uint32_t kpA = *reinterpret_cast<const uint32_t*>(kvu + (size_t)sA * 256 + c);
        const uint32_t vpA = *reinterpret_cast<const uint32_t*>(kvu + (size_t)sA * 256 + 128 + c);
        const uint32_t kpB = *reinterpret_cast<const uint32_t*>(kvu + (size_t)sB * 256 + c);
        const uint32_t vpB = *reinterpret_cast<const uint32_t*>(kvu + (size_t)sB * 256 + 128 + c);
        float eaA = 0.f, eaB = 0.f;
        if (hl < 16) {
            eaA = bf1(eau[(size_t)i * 16 + hl]);
            eaB = bf1(eau[(size_t)(i + 1) * 16 + hl]);
        }
        const float2 kA = bfp(kpA), vA = bfp(vpA), kB = bfp(kpB), vB = bfp(vpB);
        float pA = fmaf(qp.x, kA.x, fmaf(qp.y, kA.y, eaA * wqv));
        float pB = fmaf(qp.x, kB.x, fmaf(qp.y, kB.y, eaB * wqv));
        #pragma unroll
        for (int m = 1; m < 32; m <<= 1) {
            pA += __shfl_xor(pA, m, 64);
            pB += __shfl_xor(pB, m, 64);
        }
        const float exA = __expf(pA), exB = __expf(pB);
        acc0 = fmaf(exA, vA.x, fmaf(exB, vB.x, acc0));
        acc1 = fmaf(exA, vA.y, fmaf(exB, vB.y, acc1));
        den += exA + exB;
        eacc = fmaf(exA, eaA, fmaf(exB, eaB, eacc));
    }
    if (i < end) {
        const int s = srcs[i];
        const uint32_t kp = *reinterpret_cast<const uint32_t*>(kvu + (size_t)s * 256 + c);
        const uint32_t vp = *reinterpret_cast<const uint32_t*>(kvu + (size_t)s * 256 + 128 + c);
        float eaf = 0.f;
        if (hl < 16) eaf = bf1(eau[(size_t)i * 16 + hl]);
        const float2 kk = bfp(kp), vv = bfp(vp);
        float p = fmaf(qp.x, kk.x, fmaf(qp.y, kk.y, eaf * wqv));
        #pragma unroll
        for (int m = 1; m < 32; m <<= 1) p += __shfl_xor(p, m, 64);
        const float ex = __expf(p);
        acc0 = fmaf(ex, vv.x, acc0);
        acc1 = fmaf(ex, vv.y, acc1);
        den += ex;
        eacc = fmaf(ex, eaf, eacc);
    }

    #pragma unroll
    for (int r = 0; r < 16; ++r) {
        const float er = __shfl(eacc, r, 32);          // bcast within 32-half
        const float2 w = *reinterpret_cast<const float2*>(&wes[r * 128 + c]);
        acc0 = fmaf(er, w.x, acc0);
        acc1 = fmaf(er, w.y, acc1);
    }

    const float inv = 1.f / (den + 1e-16f);
    const float2 sk = *reinterpret_cast<const float2*>(skip + nb + c);
    union { __hip_bfloat16 b[2]; uint32_t u; } hp;
    hp.b[0] = __float2bfloat16(fmaxf(acc0 * inv + sk.x, 0.f));
    hp.b[1] = __float2bfloat16(fmaxf(acc1 * inv + sk.y, 0.f));
    *reinterpret_cast<uint32_t*>(hb + nb + c) = hp.u;
}

// ---------------------------------------------------------------------------
// Layer-2 aggregation (factorization + inline wq). Two edges/iter (half-waves).
// ---------------------------------------------------------------------------
__global__ __launch_bounds__(256)
void agg_l2(const int* __restrict__ off, const int* __restrict__ srcs,
            const __hip_bfloat16* __restrict__ eap,
            const float* __restrict__ We,              // [16,64]
            const float* __restrict__ q,               // [N,64], pre-scaled
            const __hip_bfloat16* __restrict__ kv,     // [N,128] k|v (bf16)
            const float* __restrict__ skip, float* __restrict__ out)
{
    __shared__ float wes[16 * 64];
    for (int i = threadIdx.x; i < 16 * 64; i += 256) wes[i] = We[i];
    __syncthreads();

    const int node = blockIdx.x * 4 + (threadIdx.x >> 6);
    const int lane = threadIdx.x & 63;
    const int half = lane >> 5;
    const int hl = lane & 31;
    const int c = hl * 2;

    const size_t nb = (size_t)node * 64;
    const float2 qp = *reinterpret_cast<const float2*>(q + nb + c);
    const uint16_t* kvu = reinterpret_cast<const uint16_t*>(kv);
    const uint16_t* eau = reinterpret_cast<const uint16_t*>(eap);

    float wqv = 0.f;
    #pragma unroll
    for (int r = 0; r < 16; ++r) {
        const float2 w = *reinterpret_cast<const float2*>(&wes[r * 64 + c]);
        float part = fmaf(w.x, qp.x, w.y * qp.y);
        #pragma unroll
        for (int m = 1; m < 32; m <<= 1) part += __shfl_xor(part, m, 64);
        if (hl == r) wqv = part;
    }

    float acc0 = 0.f, acc1 = 0.f, den = 0.f, eacc = 0.f;
    const int beg = off[node], end = off[node + 1];

    for (int i = beg; i < end; i += 2) {
        const int ii = i + half;
        const bool valid = ii < end;
        const int ie = valid ? ii : i;
        const int s = srcs[ie];
        const uint32_t kp = *reinterpret_cast<const uint32_t*>(kvu + (size_t)s * 128 + c);
        const uint32_t vp = *reinterpret_cast<const uint32_t*>(kvu + (size_t)s * 128 + 64 + c);
        float eaf = 0.f;
        if (hl < 16) eaf = bf1(eau[(size_t)ie * 16 + hl]);
        const float2 kk = bfp(kp), vv = bfp(vp);
        float p = fmaf(qp.x, kk.x, fmaf(qp.y, kk.y, eaf * wqv));
        #pragma unroll
        for (int m = 1; m < 32; m <<= 1) p += __shfl_xor(p, m, 64);
        const float ex = valid ? __expf(p) : 0.f;
        acc0 = fmaf(ex, vv.x, acc0);
        acc1 = fmaf(ex, vv.y, acc1);
        den += ex;
        eacc = fmaf(ex, eaf, eacc);
    }

    acc0 += __shfl_xor(acc0, 32, 64);
    acc1 += __shfl_xor(acc1, 32, 64);
    den  += __shfl_xor(den, 32, 64);
    eacc += __shfl_xor(eacc, 32, 64);

    #pragma unroll
    for (int r = 0; r < 16; ++r) {
        const float er = __shfl(eacc, r, 32);
        const float2 w = *reinterpret_cast<const float2*>(&wes[r * 64 + c]);
        acc0 = fmaf(er, w.x, acc0);
        acc1 = fmaf(er, w.y, acc1);
    }

    if (half == 0) {
        const float inv = 1.f / (den + 1e-16f);
        const float2 sk = *reinterpret_cast<const float2*>(skip + nb + c);
        *reinterpret_cast<float2*>(out + nb + c) =
            make_float2(acc0 * inv + sk.x, acc1 * inv + sk.y);
    }
}

extern "C" void kernel_launch(void* const* d_in, const int* in_sizes, int n_in,
                              void* d_out, int out_size, void* d_ws, size_t ws_size,
                              hipStream_t stream) {
    const float* x     = (const float*)d_in[0];
    const int*   ei    = (const int*)  d_in[1];
    const float* eattr = (const float*)d_in[2];
    const float* Wq1 = (const float*)d_in[3],  *bq1 = (const float*)d_in[4];
    const float* Wk1 = (const float*)d_in[5],  *bk1 = (const float*)d_in[6];
    const float* Wv1 = (const float*)d_in[7],  *bv1 = (const float*)d_in[8];
    const float* We1 = (const float*)d_in[9];
    const float* Ws1 = (const float*)d_in[10], *bs1 = (const float*)d_in[11];
    const float* Wq2 = (const float*)d_in[12], *bq2 = (const float*)d_in[13];
    const float* Wk2 = (const float*)d_in[14], *bk2 = (const float*)d_in[15];
    const float* Wv2 = (const float*)d_in[16], *bv2 = (const float*)d_in[17];
    const float* We2 = (const float*)d_in[18];
    const float* Ws2 = (const float*)d_in[19], *bs2 = (const float*)d_in[20];

    const int* srcp = ei;
    const int* dstp = ei + NE;

    // workspace layout (~132 MB)
    float* wsf = (float*)d_ws;
    const size_t NM1 = (size_t)NN * 128;
    float* q1    = wsf;                                       // [N,128] f32
    float* skip1 = q1 + NM1;                                  // [N,128] f32
    __hip_bfloat16* xb  = (__hip_bfloat16*)(skip1 + NM1);     // [N,128] bf16
    __hip_bfloat16* hb  = xb + NM1;                           // [N,128] bf16
    __hip_bfloat16* kv1 = hb + NM1;                           // [N,256] bf16
    __hip_bfloat16* eap = kv1 + (size_t)NN * 256;             // [E,16]  bf16
    __hip_bfloat16* Wp1 = eap + (size_t)NE * 16;              // 65536 bf16
    __hip_bfloat16* Wp2 = Wp1 + 65536;                        // 32768 bf16
    float* bcat1 = (float*)(Wp2 + 32768);                     // [512]
    float* bcat2 = bcat1 + 512;                               // [256]
    int* srcs   = (int*)(bcat2 + 256);                        // [E]
    int* cnt    = srcs + NE;                                  // [N]
    int* inc    = cnt + NN;                                   // [N]
    int* off    = inc + NN;                                   // [N+1]
    int* cursor = off + NN + 1;                               // [N]
    int* bsum   = cursor + NN;                                // [256]
    int* boff   = bsum + 256;                                 // [256]
    // layer-2 aliases (stream-ordered reuse of dead layer-1 buffers)
    float* q2    = q1;                                        // [N,64]
    float* skip2 = skip1;                                     // [N,64]
    __hip_bfloat16* kv2 = kv1;                                // [N,128]

    // ---- CSR build: hist -> hierarchical scan -> scatter ----
    hipMemsetAsync(cnt, 0, (size_t)NN * sizeof(int), stream);
    hist_dst<<<NE / 256, 256, 0, stream>>>(dstp, cnt);
    scan_blk<<<NSCB, 256, 0, stream>>>(cnt, inc, bsum);
    scan_top<<<1, 256, 0, stream>>>(bsum, boff);
    scan_fin<<<NSCB, 256, 0, stream>>>(cnt, inc, boff, off, cursor);
    scatter_edges<<<NE / 256, 256, 0, stream>>>(dstp, srcp, eattr, cursor, srcs, eap);

    // ---- input conversion + weight packing ----
    cvt_bf16<<<(NN * 128 / 8 + 255) / 256, 256, 0, stream>>>(x, xb, NN * 128 / 8);
    pack_w<128><<<(4 * 32 * 64 + 255) / 256, 256, 0, stream>>>(
        Wq1, Wk1, Wv1, Ws1, bq1, bk1, bv1, bs1, Wp1, bcat1);
    pack_w<64><<<(4 * 16 * 64 + 255) / 256, 256, 0, stream>>>(
        Wq2, Wk2, Wv2, Ws2, bq2, bk2, bv2, bs2, Wp2, bcat2);

    // ---- layer 1 ----
    gemm_mfma<128><<<NN / 16, 256, 0, stream>>>(xb, Wp1, bcat1, q1, kv1, skip1);
    agg_l1<<<NN / 4, 256, 0, stream>>>(off, srcs, eap, We1, q1, kv1, skip1, hb);

    // ---- layer 2 ----
    gemm_mfma<64><<<NN / 16, 256, 0, stream>>>(hb, Wp2, bcat2, q2, kv2, skip2);
    agg_l2<<<NN / 4, 256, 0, stream>>>(off, srcs, eap, We2, q2, kv2, skip2, (float*)d_out);
}

// Round 8
// 351.016 us; speedup vs baseline: 1.8286x; 1.0567x over previous
//
#include <hip/hip_runtime.h>
#include <hip/hip_bf16.h>

#define NN 50000
#define NE 800000
#define NSCB 196   // ceil(NN/256)

typedef __attribute__((ext_vector_type(8))) short bf16x8;
typedef __attribute__((ext_vector_type(4))) float f32x4;

__device__ __forceinline__ float2 bfp(uint32_t u) {
    union { uint32_t i; float f; } lo, hi;
    lo.i = u << 16;
    hi.i = u & 0xffff0000u;
    return make_float2(lo.f, hi.f);
}
__device__ __forceinline__ float bf1(uint16_t u) {
    union { uint32_t i; float f; } x; x.i = ((uint32_t)u) << 16; return x.f;
}

// ---------------------------------------------------------------------------
// f32 -> bf16 conversion (8 elems/thread)
// ---------------------------------------------------------------------------
__global__ __launch_bounds__(256)
void cvt_bf16(const float* __restrict__ x, __hip_bfloat16* __restrict__ xb, int n8)
{
    const int t = blockIdx.x * 256 + threadIdx.x;
    if (t >= n8) return;
    const float4 a = reinterpret_cast<const float4*>(x)[(size_t)t * 2];
    const float4 b = reinterpret_cast<const float4*>(x)[(size_t)t * 2 + 1];
    __hip_bfloat16 tmp[8] = {__float2bfloat16(a.x), __float2bfloat16(a.y),
                             __float2bfloat16(a.z), __float2bfloat16(a.w),
                             __float2bfloat16(b.x), __float2bfloat16(b.y),
                             __float2bfloat16(b.z), __float2bfloat16(b.w)};
    reinterpret_cast<uint4*>(xb)[t] = *reinterpret_cast<const uint4*>(tmp);
}

// ---------------------------------------------------------------------------
// Pack W = [Wq|Wk|Wv|Ws] into MFMA B-fragment order, bf16. bcat = biases.
// ---------------------------------------------------------------------------
template<int M>
__global__ __launch_bounds__(256)
void pack_w(const float* __restrict__ Wq, const float* __restrict__ Wk,
            const float* __restrict__ Wv, const float* __restrict__ Wsk,
            const float* __restrict__ bq, const float* __restrict__ bk,
            const float* __restrict__ bv, const float* __restrict__ bsk,
            __hip_bfloat16* __restrict__ Wp, float* __restrict__ bcat)
{
    constexpr int NFQ = M / 16;
    constexpr int NF_TOT = 4 * NFQ;
    const int t = blockIdx.x * 256 + threadIdx.x;
    if (t >= 4 * NF_TOT * 64) return;
    const int l  = t & 63;
    const int fg = (t >> 6) % NF_TOT;
    const int s  = t / (64 * NF_TOT);
    const int sec = fg / NFQ;
    const int fl  = fg % NFQ;
    const float* W = sec == 0 ? Wq : sec == 1 ? Wk : sec == 2 ? Wv : Wsk;
    const int col = fl * 16 + (l & 15);
    const int k0  = s * 32 + (l >> 4) * 8;
    __hip_bfloat16 tmp[8];
    #pragma unroll
    for (int j = 0; j < 8; ++j) tmp[j] = __float2bfloat16(W[(size_t)(k0 + j) * M + col]);
    *reinterpret_cast<uint4*>(Wp + ((size_t)(s * NF_TOT + fg) * 64 + l) * 8) =
        *reinterpret_cast<const uint4*>(tmp);
    if (s == 0 && (l >> 4) == 0) {
        const float* B = sec == 0 ? bq : sec == 1 ? bk : sec == 2 ? bv : bsk;
        bcat[fg * 16 + (l & 15)] = B[col];
    }
}

// ---------------------------------------------------------------------------
// Pack the composed map A = (1/8) * Wq (x) We^T (per-head block-diagonal) into
// MFMA B-fragment order; B0 = (1/8) * We . bq. MW = Wq cols (H*64), MO = H*16.
// ---------------------------------------------------------------------------
template<int MW, int MO>
__global__ __launch_bounds__(256)
void pack_wq(const float* __restrict__ Wq, const float* __restrict__ We,
             const float* __restrict__ bq,
             __hip_bfloat16* __restrict__ Ap, float* __restrict__ B0)
{
    constexpr int NF = MO / 16;
    const int t = blockIdx.x * 256 + threadIdx.x;
    if (t >= 4 * NF * 64) return;
    const int l  = t & 63;
    const int fg = (t >> 6) % NF;
    const int s  = t / (64 * NF);
    const int col = fg * 16 + (l & 15);
    const int h = col >> 4;
    const int r = col & 15;
    const int k0 = s * 32 + (l >> 4) * 8;
    __hip_bfloat16 tmp[8];
    #pragma unroll
    for (int jj = 0; jj < 8; ++jj) {
        float acc = 0.f;
        for (int c = 0; c < 64; ++c)
            acc += Wq[(size_t)(k0 + jj) * MW + h * 64 + c] * We[r * MW + h * 64 + c];
        tmp[jj] = __float2bfloat16(acc * 0.125f);
    }
    *reinterpret_cast<uint4*>(Ap + ((size_t)(s * NF + fg) * 64 + l) * 8) =
        *reinterpret_cast<const uint4*>(tmp);
    if (s == 0 && (l >> 4) == 0) {
        float acc = 0.f;
        for (int c = 0; c < 64; ++c) acc += bq[h * 64 + c] * We[r * MW + h * 64 + c];
        B0[col] = acc * 0.125f;
    }
}

// ---------------------------------------------------------------------------
// MFMA node GEMM: 16 rows/block, 4 waves. q (f32 *0.125), kv interleaved
// (pairs: [k2c,k2c+1][v2c,v2c+1] as adjacent uint32), skip f32.
// ---------------------------------------------------------------------------
template<int M>   // 128 (layer 1) or 64 (layer 2)
__global__ __launch_bounds__(256)
void gemm_mfma(const __hip_bfloat16* __restrict__ xb,
               const __hip_bfloat16* __restrict__ Wp,
               const float* __restrict__ bcat,
               float* __restrict__ q, __hip_bfloat16* __restrict__ kv,
               float* __restrict__ skip)
{
    constexpr int NFRAG = M / 16;
    constexpr int NF_TOT = 4 * NFRAG;
    const int wid  = threadIdx.x >> 6;
    const int l    = threadIdx.x & 63;
    const int row0 = blockIdx.x * 16;
    const int rowg = row0 + (l & 15);
    const int kb   = l >> 4;

    f32x4 acc[NFRAG];
    #pragma unroll
    for (int f = 0; f < NFRAG; ++f) acc[f] = f32x4{0.f, 0.f, 0.f, 0.f};

    const bf16x8* wp8 = reinterpret_cast<const bf16x8*>(Wp);
    #pragma unroll
    for (int s = 0; s < 4; ++s) {
        const bf16x8 a = *reinterpret_cast<const bf16x8*>(
            xb + (size_t)rowg * 128 + s * 32 + kb * 8);
        #pragma unroll
        for (int f = 0; f < NFRAG; ++f) {
            const bf16x8 b = wp8[(size_t)(s * NF_TOT + wid * NFRAG + f) * 64 + l];
            acc[f] = __builtin_amdgcn_mfma_f32_16x16x32_bf16(a, b, acc[f], 0, 0, 0);
        }
    }

    const int cl = l & 15;
    uint32_t* kvu = reinterpret_cast<uint32_t*>(kv);
    #pragma unroll
    for (int f = 0; f < NFRAG; ++f) {
        const int cg  = (wid * NFRAG + f) * 16 + cl;   // 0..4M
        const int sec = cg / M;                        // wave-uniform
        const int cm  = cg % M;
        const float bb = bcat[cg];
        #pragma unroll
        for (int j = 0; j < 4; ++j) {
            const int row = row0 + kb * 4 + j;
            const float val = acc[f][j] + bb;
            if (sec == 0)      q[(size_t)row * M + cm] = val * 0.125f;
            else if (sec == 3) skip[(size_t)row * M + cm] = val;
            else {
                const float vn = __shfl_down(val, 1, 64);
                if ((cl & 1) == 0) {
                    union { __hip_bfloat16 b[2]; uint32_t u; } pk;
                    pk.b[0] = __float2bfloat16(val);
                    pk.b[1] = __float2bfloat16(vn);
                    kvu[(size_t)row * M + (cm & ~1) + (sec == 2 ? 1 : 0)] = pk.u;
                }
            }
        }
    }
}

// ---------------------------------------------------------------------------
// wq GEMM: wq[N,MO] = xb[N,128] @ A + B0. 64 rows/block (4 waves x 16 rows).
// ---------------------------------------------------------------------------
template<int MO>
__global__ __launch_bounds__(256)
void wq_gemm(const __hip_bfloat16* __restrict__ xb,
             const __hip_bfloat16* __restrict__ Ap,
             const float* __restrict__ B0, float* __restrict__ wqo)
{
    constexpr int NF = MO / 16;
    const int wid = threadIdx.x >> 6;
    const int l   = threadIdx.x & 63;
    const int cl  = l & 15;
    const int kb  = l >> 4;
    const int row0 = blockIdx.x * 64 + wid * 16;
    int rowg = row0 + cl; if (rowg >= NN) rowg = NN - 1;

    f32x4 acc[NF];
    #pragma unroll
    for (int f = 0; f < NF; ++f) acc[f] = f32x4{0.f, 0.f, 0.f, 0.f};

    const bf16x8* ap8 = reinterpret_cast<const bf16x8*>(Ap);
    #pragma unroll
    for (int s = 0; s < 4; ++s) {
        const bf16x8 a = *reinterpret_cast<const bf16x8*>(
            xb + (size_t)rowg * 128 + s * 32 + kb * 8);
        #pragma unroll
        for (int f = 0; f < NF; ++f)
            acc[f] = __builtin_amdgcn_mfma_f32_16x16x32_bf16(
                a, ap8[(size_t)(s * NF + f) * 64 + l], acc[f], 0, 0, 0);
    }
    #pragma unroll
    for (int f = 0; f < NF; ++f) {
        const int col = f * 16 + cl;
        const float bb = B0[col];
        #pragma unroll
        for (int j = 0; j < 4; ++j) {
            const int row = row0 + kb * 4 + j;
            if (row < NN) wqo[(size_t)row * MO + col] = acc[f][j] + bb;
        }
    }
}

// ---------------------------------------------------------------------------
// CSR build: histogram -> hierarchical scan -> scatter-with-payload
// ---------------------------------------------------------------------------
__global__ __launch_bounds__(256)
void hist_dst(const int* __restrict__ dst, int* __restrict__ cnt)
{
    const int e = blockIdx.x * 256 + threadIdx.x;
    if (e < NE) atomicAdd(&cnt[dst[e]], 1);
}

__global__ __launch_bounds__(256)
void scan_blk(const int* __restrict__ cnt, int* __restrict__ inc, int* __restrict__ bsum)
{
    __shared__ int s[256];
    const int idx = blockIdx.x * 256 + threadIdx.x;
    const int v = (idx < NN) ? cnt[idx] : 0;
    s[threadIdx.x] = v;
    __syncthreads();
    #pragma unroll
    for (int d = 1; d < 256; d <<= 1) {
        const int t = (threadIdx.x >= d) ? s[threadIdx.x - d] : 0;
        __syncthreads();
        s[threadIdx.x] += t;
        __syncthreads();
    }
    if (idx < NN) inc[idx] = s[threadIdx.x];
    if (threadIdx.x == 255) bsum[blockIdx.x] = s[255];
}

__global__ __launch_bounds__(256)
void scan_top(const int* __restrict__ bsum, int* __restrict__ boff)
{
    __shared__ int s[256];
    const int v = (threadIdx.x < NSCB) ? bsum[threadIdx.x] : 0;
    s[threadIdx.x] = v;
    __syncthreads();
    #pragma unroll
    for (int d = 1; d < 256; d <<= 1) {
        const int t = (threadIdx.x >= d) ? s[threadIdx.x - d] : 0;
        __syncthreads();
        s[threadIdx.x] += t;
        __syncthreads();
    }
    boff[threadIdx.x] = s[threadIdx.x] - v;   // exclusive
}

__global__ __launch_bounds__(256)
void scan_fin(const int* __restrict__ cnt, const int* __restrict__ inc,
              const int* __restrict__ boff, int* __restrict__ off, int* __restrict__ cursor)
{
    const int idx = blockIdx.x * 256 + threadIdx.x;
    if (idx < NN) {
        const int o = inc[idx] - cnt[idx] + boff[blockIdx.x];
        off[idx] = o;
        cursor[idx] = o;
    }
    if (idx == 0) off[NN] = NE;
}

__global__ __launch_bounds__(256)
void scatter_edges(const int* __restrict__ dst, const int* __restrict__ src,
                   const float* __restrict__ ea, int* __restrict__ cursor,
                   int* __restrict__ srcs, __hip_bfloat16* __restrict__ eap)
{
    const int e = blockIdx.x * 256 + threadIdx.x;
    if (e >= NE) return;
    const int p = atomicAdd(&cursor[dst[e]], 1);
    srcs[p] = src[e];
    const float4* ea4 = reinterpret_cast<const float4*>(ea) + (size_t)e * 4;
    const float4 a0 = ea4[0], a1 = ea4[1], a2 = ea4[2], a3 = ea4[3];
    const float af[16] = {a0.x,a0.y,a0.z,a0.w, a1.x,a1.y,a1.z,a1.w,
                          a2.x,a2.y,a2.z,a2.w, a3.x,a3.y,a3.z,a3.w};
    __hip_bfloat16 tmp[16];
    #pragma unroll
    for (int r = 0; r < 16; ++r) tmp[r] = __float2bfloat16(af[r]);
    uint4* dp = reinterpret_cast<uint4*>(eap + (size_t)p * 16);
    dp[0] = *reinterpret_cast<const uint4*>(&tmp[0]);
    dp[1] = *reinterpret_cast<const uint4*>(&tmp[8]);
}

// ---------------------------------------------------------------------------
// Layer-1 aggregation. One wave per node; lane owns channel pair; head=lane>>5.
// kv interleaved (one uint2 gather per edge); wq precomputed; 4-edge unroll.
// ---------------------------------------------------------------------------
__global__ __launch_bounds__(256)
void agg_l1(const int* __restrict__ off, const int* __restrict__ srcs,
            const __hip_bfloat16* __restrict__ eap,
            const float* __restrict__ We,              // [16,128], for final proj
            const float* __restrict__ wq,              // [N,32]
            const float* __restrict__ q,               // [N,128], pre-scaled
            const __hip_bfloat16* __restrict__ kv,     // [N] interleaved pairs
            const float* __restrict__ skip, __hip_bfloat16* __restrict__ hb)
{
    __shared__ float wes[16 * 128];
    for (int i = threadIdx.x; i < 16 * 128; i += 256) wes[i] = We[i];
    __syncthreads();

    const int node = blockIdx.x * 4 + (threadIdx.x >> 6);
    const int lane = threadIdx.x & 63;
    const int hl = lane & 31;
    const int head = lane >> 5;
    const int c = lane * 2;

    const size_t nb = (size_t)node * 128;
    const float2 qp = *reinterpret_cast<const float2*>(q + nb + c);
    const float wqv = (hl < 16) ? wq[(size_t)node * 32 + head * 16 + hl] : 0.f;
    const uint32_t* kvu = reinterpret_cast<const uint32_t*>(kv);
    const uint16_t* eau = reinterpret_cast<const uint16_t*>(eap);

    float acc0 = 0.f, acc1 = 0.f, den = 0.f, eacc = 0.f;
    const int beg = off[node], end = off[node + 1];

    int i = beg;
    for (; i + 3 < end; i += 4) {
        const int s0 = srcs[i], s1 = srcs[i + 1], s2 = srcs[i + 2], s3 = srcs[i + 3];
        const uint2 x0 = *reinterpret_cast<const uint2*>(kvu + ((size_t)s0 * 64 + lane) * 2);
        const uint2 x1 = *reinterpret_cast<const uint2*>(kvu + ((size_t)s1 * 64 + lane) * 2);
        const uint2 x2 = *reinterpret_cast<const uint2*>(kvu + ((size_t)s2 * 64 + lane) * 2);
        const uint2 x3 = *reinterpret_cast<const uint2*>(kvu + ((size_t)s3 * 64 + lane) * 2);
        float e0 = 0.f, e1 = 0.f, e2 = 0.f, e3 = 0.f;
        if (hl < 16) {
            e0 = bf1(eau[(size_t)i * 16 + hl]);
            e1 = bf1(eau[(size_t)(i + 1) * 16 + hl]);
            e2 = bf1(eau[(size_t)(i + 2) * 16 + hl]);
            e3 = bf1(eau[(size_t)(i + 3) * 16 + hl]);
        }
        const float2 k0 = bfp(x0.x), k1 = bfp(x1.x), k2 = bfp(x2.x), k3 = bfp(x3.x);
        float p0 = fmaf(qp.x, k0.x, fmaf(qp.y, k0.y, e0 * wqv));
        float p1 = fmaf(qp.x, k1.x, fmaf(qp.y, k1.y, e1 * wqv));
        float p2 = fmaf(qp.x, k2.x, fmaf(qp.y, k2.y, e2 * wqv));
        float p3 = fmaf(qp.x, k3.x, fmaf(qp.y, k3.y, e3 * wqv));
        #pragma unroll
        for (int m = 1; m < 32; m <<= 1) {
            p0 += __shfl_xor(p0, m, 64);
            p1 += __shfl_xor(p1, m, 64);
            p2 += __shfl_xor(p2, m, 64);
            p3 += __shfl_xor(p3, m, 64);
        }
        const float ex0 = __expf(p0), ex1 = __expf(p1);
        const float ex2 = __expf(p2), ex3 = __expf(p3);
        const float2 v0 = bfp(x0.y), v1 = bfp(x1.y), v2 = bfp(x2.y), v3 = bfp(x3.y);
        acc0 = fmaf(ex0, v0.x, fmaf(ex1, v1.x, fmaf(ex2, v2.x, fmaf(ex3, v3.x, acc0))));
        acc1 = fmaf(ex0, v0.y, fmaf(ex1, v1.y, fmaf(ex2, v2.y, fmaf(ex3, v3.y, acc1))));
        den += (ex0 + ex1) + (ex2 + ex3);
        eacc = fmaf(ex0, e0, fmaf(ex1, e1, fmaf(ex2, e2, fmaf(ex3, e3, eacc))));
    }
    for (; i < end; ++i) {
        const int s = srcs[i];
        const uint2 x0 = *reinterpret_cast<const uint2*>(kvu + ((size_t)s * 64 + lane) * 2);
        const float eaf = (hl < 16) ? bf1(eau[(size_t)i * 16 + hl]) : 0.f;
        const float2 kk = bfp(x0.x), vv = bfp(x0.y);
        float p = fmaf(qp.x, kk.x, fmaf(qp.y, kk.y, eaf * wqv));
        #pragma unroll
        for (int m = 1; m < 32; m <<= 1) p += __shfl_xor(p, m, 64);
        const float ex = __expf(p);
        acc0 = fmaf(ex, vv.x, acc0);
        acc1 = fmaf(ex, vv.y, acc1);
        den += ex;
        eacc = fmaf(ex, eaf, eacc);
    }

    // per-node projection of accumulated ea moments through We
    #pragma unroll
    for (int r = 0; r < 16; ++r) {
        const float er = __shfl(eacc, r, 32);          // bcast within 32-half
        const float2 w = *reinterpret_cast<const float2*>(&wes[r * 128 + c]);
        acc0 = fmaf(er, w.x, acc0);
        acc1 = fmaf(er, w.y, acc1);
    }

    const float inv = 1.f / (den + 1e-16f);
    const float2 sk = *reinterpret_cast<const float2*>(skip + nb + c);
    union { __hip_bfloat16 b[2]; uint32_t u; } hp;
    hp.b[0] = __float2bfloat16(fmaxf(acc0 * inv + sk.x, 0.f));
    hp.b[1] = __float2bfloat16(fmaxf(acc1 * inv + sk.y, 0.f));
    *reinterpret_cast<uint32_t*>(hb + nb + c) = hp.u;
}

// ---------------------------------------------------------------------------
// Layer-2 aggregation. 4 edges/iter (2 per 32-half). Writes final output.
// ---------------------------------------------------------------------------
__global__ __launch_bounds__(256)
void agg_l2(const int* __restrict__ off, const int* __restrict__ srcs,
            const __hip_bfloat16* __restrict__ eap,
            const float* __restrict__ We,              // [16,64]
            const float* __restrict__ wq,              // [N,16]
            const float* __restrict__ q,               // [N,64], pre-scaled
            const __hip_bfloat16* __restrict__ kv,     // [N] interleaved pairs
            const float* __restrict__ skip, float* __restrict__ out)
{
    __shared__ float wes[16 * 64];
    for (int i = threadIdx.x; i < 16 * 64; i += 256) wes[i] = We[i];
    __syncthreads();

    const int node = blockIdx.x * 4 + (threadIdx.x >> 6);
    const int lane = threadIdx.x & 63;
    const int half = lane >> 5;
    const int hl = lane & 31;
    const int c = hl * 2;

    const size_t nb = (size_t)node * 64;
    const float2 qp = *reinterpret_cast<const float2*>(q + nb + c);
    const float wqv = (hl < 16) ? wq[(size_t)node * 16 + hl] : 0.f;
    const uint32_t* kvu = reinterpret_cast<const uint32_t*>(kv);
    const uint16_t* eau = reinterpret_cast<const uint16_t*>(eap);

    float acc0 = 0.f, acc1 = 0.f, den = 0.f, eacc = 0.f;
    const int beg = off[node], end = off[node + 1];

    for (int i = beg; i < end; i += 4) {
        const int ia = i + half * 2, ib = ia + 1;
        const bool va = ia < end, vb = ib < end;
        const int iaS = va ? ia : i, ibS = vb ? ib : i;
        const int sa = srcs[iaS], sb = srcs[ibS];
        const uint2 xa = *reinterpret_cast<const uint2*>(kvu + ((size_t)sa * 32 + hl) * 2);
        const uint2 xb = *reinterpret_cast<const uint2*>(kvu + ((size_t)sb * 32 + hl) * 2);
        float ea_ = 0.f, eb_ = 0.f;
        if (hl < 16) {
            ea_ = bf1(eau[(size_t)iaS * 16 + hl]);
            eb_ = bf1(eau[(size_t)ibS * 16 + hl]);
        }
        const float2 ka = bfp(xa.x), kb = bfp(xb.x);
        float pa = fmaf(qp.x, ka.x, fmaf(qp.y, ka.y, ea_ * wqv));
        float pb = fmaf(qp.x, kb.x, fmaf(qp.y, kb.y, eb_ * wqv));
        #pragma unroll
        for (int m = 1; m < 32; m <<= 1) {
            pa += __shfl_xor(pa, m, 64);
            pb += __shfl_xor(pb, m, 64);
        }
        const float exa = va ? __expf(pa) : 0.f;
        const float exb = vb ? __expf(pb) : 0.f;
        const float2 va_ = bfp(xa.y), vb_ = bfp(xb.y);
        acc0 = fmaf(exa, va_.x, fmaf(exb, vb_.x, acc0));
        acc1 = fmaf(exa, va_.y, fmaf(exb, vb_.y, acc1));
        den += exa + exb;
        eacc = fmaf(exa, ea_, fmaf(exb, eb_, eacc));
    }

    acc0 += __shfl_xor(acc0, 32, 64);
    acc1 += __shfl_xor(acc1, 32, 64);
    den  += __shfl_xor(den, 32, 64);
    eacc += __shfl_xor(eacc, 32, 64);

    #pragma unroll
    for (int r = 0; r < 16; ++r) {
        const float er = __shfl(eacc, r, 32);
        const float2 w = *reinterpret_cast<const float2*>(&wes[r * 64 + c]);
        acc0 = fmaf(er, w.x, acc0);
        acc1 = fmaf(er, w.y, acc1);
    }

    if (half == 0) {
        const float inv = 1.f / (den + 1e-16f);
        const float2 sk = *reinterpret_cast<const float2*>(skip + nb + c);
        *reinterpret_cast<float2*>(out + nb + c) =
            make_float2(acc0 * inv + sk.x, acc1 * inv + sk.y);
    }
}

extern "C" void kernel_launch(void* const* d_in, const int* in_sizes, int n_in,
                              void* d_out, int out_size, void* d_ws, size_t ws_size,
                              hipStream_t stream) {
    const float* x     = (const float*)d_in[0];
    const int*   ei    = (const int*)  d_in[1];
    const float* eattr = (const float*)d_in[2];
    const float* Wq1 = (const float*)d_in[3],  *bq1 = (const float*)d_in[4];
    const float* Wk1 = (const float*)d_in[5],  *bk1 = (const float*)d_in[6];
    const float* Wv1 = (const float*)d_in[7],  *bv1 = (const float*)d_in[8];
    const float* We1 = (const float*)d_in[9];
    const float* Ws1 = (const float*)d_in[10], *bs1 = (const float*)d_in[11];
    const float* Wq2 = (const float*)d_in[12], *bq2 = (const float*)d_in[13];
    const float* Wk2 = (const float*)d_in[14], *bk2 = (const float*)d_in[15];
    const float* Wv2 = (const float*)d_in[16], *bv2 = (const float*)d_in[17];
    const float* We2 = (const float*)d_in[18];
    const float* Ws2 = (const float*)d_in[19], *bs2 = (const float*)d_in[20];

    const int* srcp = ei;
    const int* dstp = ei + NE;

    // workspace layout (~140 MB)
    float* wsf = (float*)d_ws;
    const size_t NM1 = (size_t)NN * 128;
    float* q1    = wsf;                                       // [N,128] f32
    float* skip1 = q1 + NM1;                                  // [N,128] f32
    float* wqb1  = skip1 + NM1;                               // [N,32] f32
    float* wqb2  = wqb1 + (size_t)NN * 32;                    // [N,16] f32
    __hip_bfloat16* xb  = (__hip_bfloat16*)(wqb2 + (size_t)NN * 16);  // [N,128]
    __hip_bfloat16* hb  = xb + NM1;                           // [N,128] bf16
    __hip_bfloat16* kv1 = hb + NM1;                           // [N,256] bf16 interleaved
    __hip_bfloat16* eap = kv1 + (size_t)NN * 256;             // [E,16]  bf16
    __hip_bfloat16* Wp1 = eap + (size_t)NE * 16;              // 65536 bf16
    __hip_bfloat16* Wp2 = Wp1 + 65536;                        // 32768 bf16
    __hip_bfloat16* Ap1 = Wp2 + 32768;                        // 4096 bf16
    __hip_bfloat16* Ap2 = Ap1 + 4096;                         // 2048 bf16
    float* bcat1 = (float*)(Ap2 + 2048);                      // [512]
    float* bcat2 = bcat1 + 512;                               // [256]
    float* B01   = bcat2 + 256;                               // [32]
    float* B02   = B01 + 32;                                  // [16]
    int* srcs   = (int*)(B02 + 16);                           // [E]
    int* cnt    = srcs + NE;                                  // [N]
    int* inc    = cnt + NN;                                   // [N]
    int* off    = inc + NN;                                   // [N+1]
    int* cursor = off + NN + 1;                               // [N]
    int* bsum   = cursor + NN;                                // [256]
    int* boff   = bsum + 256;                                 // [256]
    // layer-2 aliases (stream-ordered reuse of dead layer-1 buffers)
    float* q2    = q1;                                        // [N,64]
    float* skip2 = skip1;                                     // [N,64]
    __hip_bfloat16* kv2 = kv1;                                // [N,128] interleaved

    // ---- CSR build: hist -> hierarchical scan -> scatter ----
    hipMemsetAsync(cnt, 0, (size_t)NN * sizeof(int), stream);
    hist_dst<<<NE / 256, 256, 0, stream>>>(dstp, cnt);
    scan_blk<<<NSCB, 256, 0, stream>>>(cnt, inc, bsum);
    scan_top<<<1, 256, 0, stream>>>(bsum, boff);
    scan_fin<<<NSCB, 256, 0, stream>>>(cnt, inc, boff, off, cursor);
    scatter_edges<<<NE / 256, 256, 0, stream>>>(dstp, srcp, eattr, cursor, srcs, eap);

    // ---- input conversion + weight packing ----
    cvt_bf16<<<(NN * 128 / 8 + 255) / 256, 256, 0, stream>>>(x, xb, NN * 128 / 8);
    pack_w<128><<<(4 * 32 * 64 + 255) / 256, 256, 0, stream>>>(
        Wq1, Wk1, Wv1, Ws1, bq1, bk1, bv1, bs1, Wp1, bcat1);
    pack_w<64><<<(4 * 16 * 64 + 255) / 256, 256, 0, stream>>>(
        Wq2, Wk2, Wv2, Ws2, bq2, bk2, bv2, bs2, Wp2, bcat2);
    pack_wq<128, 32><<<2, 256, 0, stream>>>(Wq1, We1, bq1, Ap1, B01);
    pack_wq<64, 16><<<1, 256, 0, stream>>>(Wq2, We2, bq2, Ap2, B02);

    // ---- layer 1 ----
    gemm_mfma<128><<<NN / 16, 256, 0, stream>>>(xb, Wp1, bcat1, q1, kv1, skip1);
    wq_gemm<32><<<(NN + 63) / 64, 256, 0, stream>>>(xb, Ap1, B01, wqb1);
    agg_l1<<<NN / 4, 256, 0, stream>>>(off, srcs, eap, We1, wqb1, q1, kv1, skip1, hb);

    // ---- layer 2 ----
    gemm_mfma<64><<<NN / 16, 256, 0, stream>>>(hb, Wp2, bcat2, q2, kv2, skip2);
    wq_gemm<16><<<(NN + 63) / 64, 256, 0, stream>>>(hb, Ap2, B02, wqb2);
    agg_l2<<<NN / 4, 256, 0, stream>>>(off, srcs, eap, We2, wqb2, q2, kv2, skip2, (float*)d_out);
}